// Round 4
// baseline (591.509 us; speedup 1.0000x reference)
//
#include <hip/hip_runtime.h>
#include <math.h>

// ---------------------------------------------------------------------------
// HyperMTANPro fused hypernetwork-MLP, MI355X (gfx950) — round 4.
//
// Single persistent kernel, 256 blocks x 512 threads, manual grid barriers.
// Refold: pbmm(x, hx@Wh+bh) + (hx@Wb+bb)  ==  [y (x) xa] @ Wfold
//   y = [hyper_x, 1] (H=11), xa = [x, 1, 0-pad] (NP mult of 32), k = h*NP+n.
// Phase 0 packs all weights into fp16 MFMA B-frag streaming order (blob in
// d_ws), computes g0, and initializes activation pad columns. Then 7 GEMM
// phases (g1,L0,L1,L2,L3,LE,LL) separated by grid barriers; activations live
// in global f16 buffers (L2-resident). Wave task = (row-tile of 16 samples,
// col-tile of 16). A-frags hoisted once per wave (NPS loads) and reused
// across all h with per-row y-scale; B streams 1KB frags from the blob.
// Per-CU weight traffic ~16x lower than the 64-persistent-block round-3
// structure (which was L2-port-bound at ~21us floor).
//
// Barrier: monotone counter in d_ws (memset to 0 each launch), device-scope
// atomicAdd + acquire-spin; __threadfence before arrival for cross-XCD
// visibility. All 256 blocks are co-resident (launch_bounds(512,4), 0 LDS).
// ---------------------------------------------------------------------------

typedef _Float16 f16x8 __attribute__((ext_vector_type(8)));
typedef float    f32x4 __attribute__((ext_vector_type(4)));

#define NBLK 256
#define NTHR 512
#define NTOT (NBLK * NTHR)     // 131072 threads

// blob half-offsets (prep layout, identical to round 3)
#define OFF_G1 0
#define OFF_L0 73728
#define OFF_L1 479232
#define OFF_L2 704512
#define OFF_L3 929792
#define OFF_LE 1380352
#define OFF_LL 1583104
#define TOTAL_CHUNKS 200000    // 16B fragments; blob = 3.2 MB

// d_ws byte offsets (all 64B aligned)
#define WS_XA0 3200000         // [1024][288] f16  g0 out (+aug/pad)
#define WS_XG1 3789824         // [1024][256] f16  g1 out
#define WS_XL0 4314112         // [1024][160] f16  L0 out
#define WS_XL1 4641792         // [1024][160] f16  L1 out
#define WS_XL2 4969472         // [1024][160] f16  L2 out
#define WS_XA3 5297152         // [1024][288] f16  mask*g1
#define WS_XAE 5886976         // [1024][96]  f16  extractor out
#define WS_BAR 6083584         // int barrier counter (memset 0 per launch)

// ---------------------------- weight prep (device fn) ----------------------

template<int N, int NP, int Mp, int M, int H>
__device__ __forceinline__ void prep_layer(int lci,
    const float* __restrict__ Wm, const float* __restrict__ bm,
    const float* __restrict__ Wb, const float* __restrict__ bb,
    _Float16* __restrict__ dst)
{
    constexpr int CT = Mp / 16;
    const int l  = lci & 63;
    const int sc = lci >> 6;
    const int c  = sc & (CT - 1);
    const int s  = sc / CT;
    const int col = c * 16 + (l & 15);
    const int k0  = s * 32 + ((l >> 4) << 3);
    const int h   = k0 / NP;
    const int n0  = k0 - h * NP;

    f16x8 v;
    #pragma unroll
    for (int i = 0; i < 8; ++i) {
        const int n = n0 + i;
        float w = 0.f;
        if (col < M && n <= N) {
            if (H == 11 && h < 10)
                w = (n < N) ? Wm[h * (N * M) + n * M + col] : Wb[h * M + col];
            else
                w = (n < N) ? bm[n * M + col] : bb[col];
        }
        v[i] = (_Float16)w;
    }
    *(f16x8*)(dst + (size_t)lci * 8) = v;
}

// ---------------------------- grid barrier ---------------------------------

__device__ __forceinline__ void grid_barrier(int* bar, int gen)
{
    __threadfence();                      // flush this thread's global writes
    __syncthreads();
    if (threadIdx.x == 0) {
        __hip_atomic_fetch_add(bar, 1, __ATOMIC_ACQ_REL, __HIP_MEMORY_SCOPE_AGENT);
        while (__hip_atomic_load(bar, __ATOMIC_ACQUIRE, __HIP_MEMORY_SCOPE_AGENT)
               < gen * NBLK)
            __builtin_amdgcn_s_sleep(1);
    }
    __syncthreads();
}

// ---------------------------- layer wave -----------------------------------
// One wave computes a 16x16 output tile: rows rb*16..+15, cols ct*16..+15.
// A-frags (NPS) hoisted and reused across h; B streams from blob.

template<int NPS, int H, int CT, bool SCALE, int STRIDE>
__device__ __forceinline__ f32x4 layer_wave(
    const _Float16* __restrict__ Wl,    // layer blob base
    const _Float16* __restrict__ src,   // activation buffer [1024][STRIDE]
    const float* __restrict__ hx,       // hyper_x [1024][10]
    int rb, int ct, int lane)
{
    const int r = lane & 15;
    const int q = lane >> 4;
    const int row = rb * 16 + r;

    f16x8 xv[NPS];
    const _Float16* xrow = src + (size_t)row * STRIDE + q * 8;
    #pragma unroll
    for (int j = 0; j < NPS; ++j) xv[j] = *(const f16x8*)(xrow + j * 32);

    _Float16 ys[H];
    if (SCALE) {
        #pragma unroll
        for (int h = 0; h < H; ++h)
            ys[h] = (h < 10) ? (_Float16)hx[row * 10 + h] : (_Float16)1.f;
    }

    f32x4 acc0 = {0.f, 0.f, 0.f, 0.f}, acc1 = acc0;
    const _Float16* wbase = Wl + ((size_t)ct * 64 + lane) * 8;
    #pragma unroll
    for (int h = 0; h < H; ++h) {
        #pragma unroll
        for (int j = 0; j < NPS; ++j) {
            f16x8 a = xv[j];
            if (SCALE) {
                const _Float16 s = ys[h];
                f16x8 y8 = {s, s, s, s, s, s, s, s};
                a = a * y8;
            }
            f16x8 b = *(const f16x8*)(wbase + (size_t)((h * NPS + j) * CT) * 512);
            if ((h * NPS + j) & 1)
                acc1 = __builtin_amdgcn_mfma_f32_16x16x32_f16(a, b, acc1, 0, 0, 0);
            else
                acc0 = __builtin_amdgcn_mfma_f32_16x16x32_f16(a, b, acc0, 0, 0, 0);
        }
    }
    return acc0 + acc1;
}

// ---------------------------- mega kernel ----------------------------------

__global__ __launch_bounds__(NTHR, 4) void mega_kernel(
    const float* __restrict__ hx,   const float* __restrict__ mlp_x,
    const float* __restrict__ G0w,  const float* __restrict__ G0b,
    const float* __restrict__ G1w,  const float* __restrict__ G1b,
    const float* __restrict__ Wmw0, const float* __restrict__ bmw0,
    const float* __restrict__ Wmb0, const float* __restrict__ bmb0,
    const float* __restrict__ Wmw1, const float* __restrict__ bmw1,
    const float* __restrict__ Wmb1, const float* __restrict__ bmb1,
    const float* __restrict__ Wmw2, const float* __restrict__ bmw2,
    const float* __restrict__ Wmb2, const float* __restrict__ bmb2,
    const float* __restrict__ Wmw3, const float* __restrict__ bmw3,
    const float* __restrict__ Wmb3, const float* __restrict__ bmb3,
    const float* __restrict__ Wew,  const float* __restrict__ bew,
    const float* __restrict__ Web,  const float* __restrict__ beb,
    const float* __restrict__ Wlw,  const float* __restrict__ blw,
    const float* __restrict__ Wlb,  const float* __restrict__ blb,
    char* __restrict__ ws, float* __restrict__ out)
{
    const int tid  = threadIdx.x;
    const int bid  = blockIdx.x;
    const int id   = bid * NTHR + tid;
    const int lane = tid & 63;
    const int gw   = bid * 8 + (tid >> 6);
    const int r = lane & 15, q = lane >> 4;

    _Float16* Wp  = (_Float16*)ws;
    _Float16* xa0 = (_Float16*)(ws + WS_XA0);
    _Float16* xg1 = (_Float16*)(ws + WS_XG1);
    _Float16* xl0 = (_Float16*)(ws + WS_XL0);
    _Float16* xl1 = (_Float16*)(ws + WS_XL1);
    _Float16* xl2 = (_Float16*)(ws + WS_XL2);
    _Float16* xa3 = (_Float16*)(ws + WS_XA3);
    _Float16* xae = (_Float16*)(ws + WS_XAE);
    int* bar = (int*)(ws + WS_BAR);

    // ---------------- P0: weight prep + g0 + pad init ----------------------
    for (int ci = id; ci < TOTAL_CHUNKS; ci += NTOT) {
        if (ci < 9216)
            prep_layer<256,288,256,256, 1>(ci,          nullptr, G1w, nullptr, G1b, Wp + OFF_G1);
        else if (ci < 59904)
            prep_layer<256,288,128,128,11>(ci - 9216,   Wmw0, bmw0, Wmb0, bmb0, Wp + OFF_L0);
        else if (ci < 88064)
            prep_layer<128,160,128,128,11>(ci - 59904,  Wmw1, bmw1, Wmb1, bmb1, Wp + OFF_L1);
        else if (ci < 116224)
            prep_layer<128,160,128,128,11>(ci - 88064,  Wmw2, bmw2, Wmb2, bmb2, Wp + OFF_L2);
        else if (ci < 172544)
            prep_layer<128,160,256,256,11>(ci - 116224, Wmw3, bmw3, Wmb3, bmb3, Wp + OFF_L3);
        else if (ci < 197888)
            prep_layer<256,288, 64, 64,11>(ci - 172544, Wew,  bew,  Web,  beb,  Wp + OFF_LE);
        else
            prep_layer< 64, 96, 16,  8,11>(ci - 197888, Wlw,  blw,  Wlb,  blb,  Wp + OFF_LL);
    }
    // g0 = relu(mlp_x @ G0w + G0b) -> xa0   (2 outputs per thread)
    #pragma unroll
    for (int half = 0; half < 2; ++half) {
        const int row = (id >> 8) + half * 512;
        const int col = id & 255;
        float acc = G0b[col];
        #pragma unroll
        for (int n = 0; n < 9; ++n)
            acc = fmaf(mlp_x[row * 9 + n], G0w[n * 256 + col], acc);
        xa0[(size_t)row * 288 + col] = (_Float16)fmaxf(acc, 0.f);
    }
    // pad columns: slot M = 1.0 (augment), rest 0  (all buffers have NP-M=32)
    if (id < 32768) {
        const int rr = id >> 5, o = id & 31;
        const _Float16 v = (o == 0) ? (_Float16)1.f : (_Float16)0.f;
        xa0[(size_t)rr * 288 + 256 + o] = v;
        xl0[(size_t)rr * 160 + 128 + o] = v;
        xl1[(size_t)rr * 160 + 128 + o] = v;
        xl2[(size_t)rr * 160 + 128 + o] = v;
        xa3[(size_t)rr * 288 + 256 + o] = v;
        xae[(size_t)rr * 96  +  64 + o] = v;
    }
    grid_barrier(bar, 1);

    // ---------------- P1: g1 (1024 waves) + L0 (512 waves) -----------------
    if (gw < 1024) {
        const int rb = gw >> 4, ct = gw & 15;
        f32x4 acc = layer_wave<9, 1, 16, false, 288>(Wp + OFF_G1, xa0, hx, rb, ct, lane);
        #pragma unroll
        for (int t = 0; t < 4; ++t)
            xg1[(size_t)(rb * 16 + q * 4 + t) * 256 + ct * 16 + r] =
                (_Float16)fmaxf(acc[t], 0.f);
    } else if (gw < 1536) {
        const int t2 = gw - 1024, rb = t2 >> 3, ct = t2 & 7;
        f32x4 acc = layer_wave<9, 11, 8, true, 288>(Wp + OFF_L0, xa0, hx, rb, ct, lane);
        #pragma unroll
        for (int t = 0; t < 4; ++t)
            xl0[(size_t)(rb * 16 + q * 4 + t) * 160 + ct * 16 + r] =
                (_Float16)fmaxf(acc[t], 0.f);
    }
    grid_barrier(bar, 2);

    // ---------------- P2: L1 (512 waves) -----------------------------------
    if (gw < 512) {
        const int rb = gw >> 3, ct = gw & 7;
        f32x4 acc = layer_wave<5, 11, 8, true, 160>(Wp + OFF_L1, xl0, hx, rb, ct, lane);
        #pragma unroll
        for (int t = 0; t < 4; ++t)
            xl1[(size_t)(rb * 16 + q * 4 + t) * 160 + ct * 16 + r] =
                (_Float16)fmaxf(acc[t], 0.f);
    }
    grid_barrier(bar, 3);

    // ---------------- P3: L2 (512 waves) -----------------------------------
    if (gw < 512) {
        const int rb = gw >> 3, ct = gw & 7;
        f32x4 acc = layer_wave<5, 11, 8, true, 160>(Wp + OFF_L2, xl1, hx, rb, ct, lane);
        #pragma unroll
        for (int t = 0; t < 4; ++t)
            xl2[(size_t)(rb * 16 + q * 4 + t) * 160 + ct * 16 + r] =
                (_Float16)fmaxf(acc[t], 0.f);
    }
    grid_barrier(bar, 4);

    // ---------------- P4: L3 mask (1024 waves): sigmoid(.)*g1 --------------
    if (gw < 1024) {
        const int rb = gw >> 4, ct = gw & 15;
        f32x4 acc = layer_wave<5, 11, 16, true, 160>(Wp + OFF_L3, xl2, hx, rb, ct, lane);
        #pragma unroll
        for (int t = 0; t < 4; ++t) {
            const int row = rb * 16 + q * 4 + t, col = ct * 16 + r;
            float v = 1.f / (1.f + __expf(-acc[t]));
            v *= (float)xg1[(size_t)row * 256 + col];
            xa3[(size_t)row * 288 + col] = (_Float16)v;
        }
    }
    grid_barrier(bar, 5);

    // ---------------- P5: LE extractor (256 waves) --------------------------
    if (gw < 256) {
        const int rb = gw >> 2, ct = gw & 3;
        f32x4 acc = layer_wave<9, 11, 4, true, 288>(Wp + OFF_LE, xa3, hx, rb, ct, lane);
        #pragma unroll
        for (int t = 0; t < 4; ++t)
            xae[(size_t)(rb * 16 + q * 4 + t) * 96 + ct * 16 + r] =
                (_Float16)fmaxf(acc[t], 0.f);
    }
    grid_barrier(bar, 6);

    // ---------------- P6: LL last (64 waves) -> out f32 ---------------------
    if (gw < 64) {
        const int rb = gw;
        f32x4 acc = layer_wave<3, 11, 1, true, 96>(Wp + OFF_LL, xae, hx, rb, 0, lane);
        if (r < 8) {
            #pragma unroll
            for (int t = 0; t < 4; ++t)
                out[(size_t)(rb * 16 + q * 4 + t) * 8 + r] = acc[t];
        }
    }
}

// ---------------------------- launch ---------------------------------------

extern "C" void kernel_launch(void* const* d_in, const int* in_sizes, int n_in,
                              void* d_out, int out_size, void* d_ws, size_t ws_size,
                              hipStream_t stream)
{
    char* ws = (char*)d_ws;
    hipMemsetAsync(ws + WS_BAR, 0, 64, stream);   // barrier counter = 0

    mega_kernel<<<NBLK, NTHR, 0, stream>>>(
        (const float*)d_in[0],  (const float*)d_in[1],
        (const float*)d_in[2],  (const float*)d_in[3],
        (const float*)d_in[4],  (const float*)d_in[5],
        (const float*)d_in[6],  (const float*)d_in[7],  (const float*)d_in[8],  (const float*)d_in[9],
        (const float*)d_in[10], (const float*)d_in[11], (const float*)d_in[12], (const float*)d_in[13],
        (const float*)d_in[14], (const float*)d_in[15], (const float*)d_in[16], (const float*)d_in[17],
        (const float*)d_in[18], (const float*)d_in[19], (const float*)d_in[20], (const float*)d_in[21],
        (const float*)d_in[22], (const float*)d_in[23], (const float*)d_in[24], (const float*)d_in[25],
        (const float*)d_in[26], (const float*)d_in[27], (const float*)d_in[28], (const float*)d_in[29],
        ws, (float*)d_out);
}

// Round 5
// 80.024 us; speedup vs baseline: 7.3916x; 7.3916x over previous
//
#include <hip/hip_runtime.h>
#include <math.h>

// ---------------------------------------------------------------------------
// HyperMTANPro fused hypernetwork-MLP, MI355X (gfx950) — round 5.
//
// Multi-kernel phase pipeline (7 kernels, graph-captured). Kernel boundaries
// provide cross-XCD coherence (no manual barriers — round 4's acquire-spin
// invalidate-storm cost 600us).
//
// Refold: pbmm(x, hx@Wh+bh) + (hx@Wb+bb)  ==  [y (x) xa] @ Wfold
//   y = [hyper_x, 1] (H=11), xa = [x, 1, 0-pad] (NP mult of 32), k = h*NP+n.
// K0 packs weights into fp16 MFMA B-frag streaming order + computes g0 + pad
// cols. K1..K6: one layer each (L0,L1,L2,L3+g1,LE,LL). Wave task = 2 row-
// tiles (32 samples) x 16 cols; B-frag loaded once, used twice (2 MFMAs).
// Task map ct = t>>5 so each block reads ONE column-slice of the layer blob
// (~0.1-0.2MB/CU vs 3.2MB/CU in the single-fused-kernel design whose L1-fill
// port floor was ~21us). g1 is recomputed inside K4 (L3) from xa0 — saves a
// phase and the xg1 buffer round-trip.
// ---------------------------------------------------------------------------

typedef _Float16 f16x8 __attribute__((ext_vector_type(8)));
typedef float    f32x4 __attribute__((ext_vector_type(4)));

// blob half-offsets
#define OFF_G1 0
#define OFF_L0 73728
#define OFF_L1 479232
#define OFF_L2 704512
#define OFF_L3 929792
#define OFF_LE 1380352
#define OFF_LL 1583104
#define TOTAL_CHUNKS 200000    // 16B fragments; blob = 3.2 MB

// activation buffers, half-offsets inside d_ws
#define HA0 1600000            // [1024][288] g0 (+aug/pad)
#define HL0 2157056            // [1024][160] L0 out
#define HL1 2320896            // [1024][160] L1 out
#define HL2 2484736            // [1024][160] L2 out
#define HA3 2648576            // [1024][288] mask*g1
#define HAE 2943488            // [1024][96]  extractor out

// ---------------------------- weight prep (device fn) ----------------------

template<int N, int NP, int Mp, int M, int H>
__device__ __forceinline__ void prep_layer(int lci,
    const float* __restrict__ Wm, const float* __restrict__ bm,
    const float* __restrict__ Wb, const float* __restrict__ bb,
    _Float16* __restrict__ dst)
{
    constexpr int CT = Mp / 16;
    const int l  = lci & 63;
    const int sc = lci >> 6;
    const int c  = sc & (CT - 1);
    const int s  = sc / CT;
    const int col = c * 16 + (l & 15);
    const int k0  = s * 32 + ((l >> 4) << 3);
    const int h   = k0 / NP;
    const int n0  = k0 - h * NP;

    f16x8 v;
    #pragma unroll
    for (int i = 0; i < 8; ++i) {
        const int n = n0 + i;
        float w = 0.f;
        if (col < M && n <= N) {
            if (H == 11 && h < 10)
                w = (n < N) ? Wm[h * (N * M) + n * M + col] : Wb[h * M + col];
            else
                w = (n < N) ? bm[n * M + col] : bb[col];
        }
        v[i] = (_Float16)w;
    }
    *(f16x8*)(dst + (size_t)lci * 8) = v;
}

__global__ __launch_bounds__(512) void k0_prep(
    const float* __restrict__ hx,   const float* __restrict__ mlp_x,
    const float* __restrict__ G0w,  const float* __restrict__ G0b,
    const float* __restrict__ G1w,  const float* __restrict__ G1b,
    const float* __restrict__ Wmw0, const float* __restrict__ bmw0,
    const float* __restrict__ Wmb0, const float* __restrict__ bmb0,
    const float* __restrict__ Wmw1, const float* __restrict__ bmw1,
    const float* __restrict__ Wmb1, const float* __restrict__ bmb1,
    const float* __restrict__ Wmw2, const float* __restrict__ bmw2,
    const float* __restrict__ Wmb2, const float* __restrict__ bmb2,
    const float* __restrict__ Wmw3, const float* __restrict__ bmw3,
    const float* __restrict__ Wmb3, const float* __restrict__ bmb3,
    const float* __restrict__ Wew,  const float* __restrict__ bew,
    const float* __restrict__ Web,  const float* __restrict__ beb,
    const float* __restrict__ Wlw,  const float* __restrict__ blw,
    const float* __restrict__ Wlb,  const float* __restrict__ blb,
    char* __restrict__ ws)
{
    const int id = blockIdx.x * 512 + threadIdx.x;   // 131072 threads
    _Float16* Wp  = (_Float16*)ws;
    _Float16* xa0 = Wp + HA0;
    _Float16* xl0 = Wp + HL0;
    _Float16* xl1 = Wp + HL1;
    _Float16* xl2 = Wp + HL2;
    _Float16* xa3 = Wp + HA3;
    _Float16* xae = Wp + HAE;

    for (int ci = id; ci < TOTAL_CHUNKS; ci += 131072) {
        if (ci < 9216)
            prep_layer<256,288,256,256, 1>(ci,          nullptr, G1w, nullptr, G1b, Wp + OFF_G1);
        else if (ci < 59904)
            prep_layer<256,288,128,128,11>(ci - 9216,   Wmw0, bmw0, Wmb0, bmb0, Wp + OFF_L0);
        else if (ci < 88064)
            prep_layer<128,160,128,128,11>(ci - 59904,  Wmw1, bmw1, Wmb1, bmb1, Wp + OFF_L1);
        else if (ci < 116224)
            prep_layer<128,160,128,128,11>(ci - 88064,  Wmw2, bmw2, Wmb2, bmb2, Wp + OFF_L2);
        else if (ci < 172544)
            prep_layer<128,160,256,256,11>(ci - 116224, Wmw3, bmw3, Wmb3, bmb3, Wp + OFF_L3);
        else if (ci < 197888)
            prep_layer<256,288, 64, 64,11>(ci - 172544, Wew,  bew,  Web,  beb,  Wp + OFF_LE);
        else
            prep_layer< 64, 96, 16,  8,11>(ci - 197888, Wlw,  blw,  Wlb,  blb,  Wp + OFF_LL);
    }
    // g0 = relu(mlp_x @ G0w + G0b) -> xa0
    #pragma unroll
    for (int half = 0; half < 2; ++half) {
        const int row = (id >> 8) + half * 512;
        const int col = id & 255;
        float acc = G0b[col];
        #pragma unroll
        for (int n = 0; n < 9; ++n)
            acc = fmaf(mlp_x[row * 9 + n], G0w[n * 256 + col], acc);
        xa0[(size_t)row * 288 + col] = (_Float16)fmaxf(acc, 0.f);
    }
    // pad columns: slot M = 1.0 (augment), rest 0
    if (id < 32768) {
        const int rr = id >> 5, o = id & 31;
        const _Float16 v = (o == 0) ? (_Float16)1.f : (_Float16)0.f;
        xa0[(size_t)rr * 288 + 256 + o] = v;
        xl0[(size_t)rr * 160 + 128 + o] = v;
        xl1[(size_t)rr * 160 + 128 + o] = v;
        xl2[(size_t)rr * 160 + 128 + o] = v;
        xa3[(size_t)rr * 288 + 256 + o] = v;
        xae[(size_t)rr * 96  +  64 + o] = v;
    }
}

// ---------------------------- layer wave (2 row-tiles) ---------------------

template<int NPS, int H, int CT, bool SCALE, int STRIDE>
__device__ __forceinline__ void layer_wave2(
    const _Float16* __restrict__ Wl,    // layer blob base
    const _Float16* __restrict__ src,   // activation [1024][STRIDE]
    const float* __restrict__ hx,       // hyper_x [1024][10]
    int rbg, int ct, int lane, f32x4 acc[2])
{
    const int r = lane & 15, q = lane >> 4;
    const int row0 = rbg * 32 + r;

    f16x8 xv0[NPS], xv1[NPS];
    const _Float16* x0 = src + (size_t)row0 * STRIDE + q * 8;
    const _Float16* x1 = x0 + 16 * STRIDE;
    #pragma unroll
    for (int j = 0; j < NPS; ++j) {
        xv0[j] = *(const f16x8*)(x0 + j * 32);
        xv1[j] = *(const f16x8*)(x1 + j * 32);
    }
    _Float16 ys0[H], ys1[H];
    if (SCALE) {
        #pragma unroll
        for (int h = 0; h < H; ++h) {
            ys0[h] = (h < 10) ? (_Float16)hx[row0 * 10 + h]        : (_Float16)1.f;
            ys1[h] = (h < 10) ? (_Float16)hx[(row0 + 16) * 10 + h] : (_Float16)1.f;
        }
    }
    f32x4 z = {0.f, 0.f, 0.f, 0.f};
    acc[0] = z; acc[1] = z;
    const _Float16* wbase = Wl + ((size_t)ct * 64 + lane) * 8;
    #pragma unroll
    for (int h = 0; h < H; ++h) {
        #pragma unroll
        for (int j = 0; j < NPS; ++j) {
            f16x8 b = *(const f16x8*)(wbase + (size_t)((h * NPS + j) * CT) * 512);
            f16x8 a0 = xv0[j], a1 = xv1[j];
            if (SCALE) {
                const _Float16 s0 = ys0[h], s1 = ys1[h];
                f16x8 y80 = {s0, s0, s0, s0, s0, s0, s0, s0};
                f16x8 y81 = {s1, s1, s1, s1, s1, s1, s1, s1};
                a0 = a0 * y80; a1 = a1 * y81;
            }
            acc[0] = __builtin_amdgcn_mfma_f32_16x16x32_f16(a0, b, acc[0], 0, 0, 0);
            acc[1] = __builtin_amdgcn_mfma_f32_16x16x32_f16(a1, b, acc[1], 0, 0, 0);
        }
    }
}

// ---------------------------- relu layer kernels ---------------------------
// task t: ct = t>>5 (block reads one col-slice of blob), rbg = t&31.

template<int NPS, int CT, int SIN, int SOUT, int OFFW, int OFFI, int OFFO>
__global__ __launch_bounds__(512) void relu_layer_kernel(
    const float* __restrict__ hx, char* __restrict__ ws)
{
    const int tid = threadIdx.x, lane = tid & 63;
    const int t   = blockIdx.x * 8 + (tid >> 6);
    const int ct  = t >> 5, rbg = t & 31;
    const _Float16* Wp  = (const _Float16*)ws + OFFW;
    const _Float16* src = (const _Float16*)ws + OFFI;
    _Float16*       dst = (_Float16*)ws + OFFO;

    f32x4 acc[2];
    layer_wave2<NPS, 11, CT, true, SIN>(Wp, src, hx, rbg, ct, lane, acc);

    const int r = lane & 15, q = lane >> 4;
    #pragma unroll
    for (int tt = 0; tt < 2; ++tt)
        #pragma unroll
        for (int t4 = 0; t4 < 4; ++t4)
            dst[(size_t)(rbg * 32 + tt * 16 + q * 4 + t4) * SOUT + ct * 16 + r] =
                (_Float16)fmaxf(acc[tt][t4], 0.f);
}

// K4: L3 mask + inline g1 recompute: xa3 = sigmoid(L3) * relu(g1)
__global__ __launch_bounds__(512) void k4_mask(
    const float* __restrict__ hx, char* __restrict__ ws)
{
    const int tid = threadIdx.x, lane = tid & 63;
    const int t   = blockIdx.x * 8 + (tid >> 6);   // 0..511
    const int ct  = t >> 5, rbg = t & 31;
    const _Float16* Wp = (const _Float16*)ws;
    _Float16* xa3 = (_Float16*)ws + HA3;

    f32x4 g1a[2];
    layer_wave2<9, 1, 16, false, 288>(Wp + OFF_G1, (const _Float16*)ws + HA0,
                                      hx, rbg, ct, lane, g1a);
    f32x4 ma[2];
    layer_wave2<5, 11, 16, true, 160>(Wp + OFF_L3, (const _Float16*)ws + HL2,
                                      hx, rbg, ct, lane, ma);

    const int r = lane & 15, q = lane >> 4;
    #pragma unroll
    for (int tt = 0; tt < 2; ++tt)
        #pragma unroll
        for (int t4 = 0; t4 < 4; ++t4) {
            const int row = rbg * 32 + tt * 16 + q * 4 + t4;
            const float g1v = fmaxf(g1a[tt][t4], 0.f);
            const float m   = 1.f / (1.f + __expf(-ma[tt][t4]));
            xa3[(size_t)row * 288 + ct * 16 + r] = (_Float16)(m * g1v);
        }
}

// K6: LL last layer -> out (f32, cols 0..7)
__global__ __launch_bounds__(512) void k6_last(
    const float* __restrict__ hx, char* __restrict__ ws, float* __restrict__ out)
{
    const int tid = threadIdx.x, lane = tid & 63;
    const int t   = blockIdx.x * 8 + (tid >> 6);   // 0..31
    const int rbg = t & 31;
    const _Float16* Wp = (const _Float16*)ws;

    f32x4 acc[2];
    layer_wave2<3, 11, 1, true, 96>(Wp + OFF_LL, (const _Float16*)ws + HAE,
                                    hx, rbg, 0, lane, acc);

    const int r = lane & 15, q = lane >> 4;
    if (r < 8) {
        #pragma unroll
        for (int tt = 0; tt < 2; ++tt)
            #pragma unroll
            for (int t4 = 0; t4 < 4; ++t4)
                out[(size_t)(rbg * 32 + tt * 16 + q * 4 + t4) * 8 + r] = acc[tt][t4];
    }
}

// ---------------------------- launch ---------------------------------------

extern "C" void kernel_launch(void* const* d_in, const int* in_sizes, int n_in,
                              void* d_out, int out_size, void* d_ws, size_t ws_size,
                              hipStream_t stream)
{
    const float* hx = (const float*)d_in[0];
    char* ws = (char*)d_ws;

    k0_prep<<<256, 512, 0, stream>>>(
        hx,                     (const float*)d_in[1],
        (const float*)d_in[2],  (const float*)d_in[3],
        (const float*)d_in[4],  (const float*)d_in[5],
        (const float*)d_in[6],  (const float*)d_in[7],  (const float*)d_in[8],  (const float*)d_in[9],
        (const float*)d_in[10], (const float*)d_in[11], (const float*)d_in[12], (const float*)d_in[13],
        (const float*)d_in[14], (const float*)d_in[15], (const float*)d_in[16], (const float*)d_in[17],
        (const float*)d_in[18], (const float*)d_in[19], (const float*)d_in[20], (const float*)d_in[21],
        (const float*)d_in[22], (const float*)d_in[23], (const float*)d_in[24], (const float*)d_in[25],
        (const float*)d_in[26], (const float*)d_in[27], (const float*)d_in[28], (const float*)d_in[29],
        ws);

    // L0: xa0[288] -> xl0[160], CT=8, NPS=9
    relu_layer_kernel<9, 8, 288, 160, OFF_L0, HA0, HL0><<<32, 512, 0, stream>>>(hx, ws);
    // L1: xl0 -> xl1, CT=8, NPS=5
    relu_layer_kernel<5, 8, 160, 160, OFF_L1, HL0, HL1><<<32, 512, 0, stream>>>(hx, ws);
    // L2: xl1 -> xl2
    relu_layer_kernel<5, 8, 160, 160, OFF_L2, HL1, HL2><<<32, 512, 0, stream>>>(hx, ws);
    // L3 + g1 -> xa3
    k4_mask<<<64, 512, 0, stream>>>(hx, ws);
    // LE: xa3[288] -> xae[96], CT=4, NPS=9
    relu_layer_kernel<9, 4, 288, 96, OFF_LE, HA3, HAE><<<16, 512, 0, stream>>>(hx, ws);
    // LL -> out
    k6_last<<<4, 512, 0, stream>>>(hx, ws, (float*)d_out);
}